// Round 2
// baseline (1097.089 us; speedup 1.0000x reference)
//
#include <hip/hip_runtime.h>
#include <math.h>

#define NE 64            // experts
#define TPB 128          // tokens per block (kernel 1)
#define KC 64            // K chunk
#define HDIM 4096
#define SEQ 4096
#define NTOK 32768       // B*S
#define CAP 128          // expert capacity
#define LSTRIDE 65       // logits row stride in doubles

// ---------------------------------------------------------------------------
// Kernel 1: logits GEMM (fp64 accumulate) + softmax + top2 + loss partials
//           + zero dispatch/combine
// grid = 256 blocks (128 tokens each), 256 threads
// ---------------------------------------------------------------------------
__global__ __launch_bounds__(256) void k_router(
    const float* __restrict__ hs, const float* __restrict__ rw,
    float* __restrict__ dispatch, float* __restrict__ combine,
    float* __restrict__ probs_out,
    int* __restrict__ idx_buf, float* __restrict__ wgt_buf,
    float* __restrict__ partials)
{
    // 8320 doubles = 66.56 KiB. GEMM staging uses it as floats (48 KiB),
    // logits epilogue as doubles [128][LSTRIDE].
    __shared__ double smemd[TPB * LSTRIDE];
    float* shh = (float*)smemd;            // [KC][128] hidden chunk (fp32)
    float* sww = (float*)smemd + KC * TPB; // [KC][64]  weight chunk (fp32)
    double* sdl = smemd;                   // logits as doubles
    __shared__ float red1[4], red2[4];

    const int tid = threadIdx.x;
    const int tokBase = blockIdx.x * TPB;

    const int eg = tid & 15;               // expert group: experts 4*eg..4*eg+3
    const int tg = tid >> 4;               // token group : tokens  8*tg..8*tg+7

    double acc[8][4];
#pragma unroll
    for (int i = 0; i < 8; ++i)
#pragma unroll
        for (int j = 0; j < 4; ++j) acc[i][j] = 0.0;

    // staging assignment
    const int t_ld = tid >> 1;             // 0..127 token row
    const int kh_off = (tid & 1) * 32;     // half of KC
    const float* hrow = hs + (size_t)(tokBase + t_ld) * HDIM + kh_off;
    const int e_ld = tid >> 2;             // 0..63 expert row
    const int kw_off = (tid & 3) * 16;     // quarter of KC
    const float* wrow = rw + (size_t)e_ld * HDIM + kw_off;

    float4 hreg[8];
    float4 wreg[4];
#pragma unroll
    for (int i = 0; i < 8; ++i) hreg[i] = *(const float4*)(hrow + i * 4);
#pragma unroll
    for (int i = 0; i < 4; ++i) wreg[i] = *(const float4*)(wrow + i * 4);

    const int nChunks = HDIM / KC;         // 64
    for (int c = 0; c < nChunks; ++c) {
        __syncthreads();
        // staged regs -> LDS (transposed to [k][x])
#pragma unroll
        for (int i = 0; i < 8; ++i) {
            int kk = kh_off + i * 4;
            shh[(kk + 0) * TPB + t_ld] = hreg[i].x;
            shh[(kk + 1) * TPB + t_ld] = hreg[i].y;
            shh[(kk + 2) * TPB + t_ld] = hreg[i].z;
            shh[(kk + 3) * TPB + t_ld] = hreg[i].w;
        }
#pragma unroll
        for (int i = 0; i < 4; ++i) {
            int kk = kw_off + i * 4;
            sww[(kk + 0) * NE + e_ld] = wreg[i].x;
            sww[(kk + 1) * NE + e_ld] = wreg[i].y;
            sww[(kk + 2) * NE + e_ld] = wreg[i].z;
            sww[(kk + 3) * NE + e_ld] = wreg[i].w;
        }
        __syncthreads();
        // prefetch next chunk while computing this one
        if (c + 1 < nChunks) {
            const float* hp = hrow + (size_t)(c + 1) * KC;
#pragma unroll
            for (int i = 0; i < 8; ++i) hreg[i] = *(const float4*)(hp + i * 4);
            const float* wp = wrow + (size_t)(c + 1) * KC;
#pragma unroll
            for (int i = 0; i < 4; ++i) wreg[i] = *(const float4*)(wp + i * 4);
        }
#pragma unroll 2
        for (int k = 0; k < KC; ++k) {
            float4 w  = *(const float4*)&sww[k * NE + 4 * eg];
            float4 h0 = *(const float4*)&shh[k * TPB + 8 * tg];
            float4 h1 = *(const float4*)&shh[k * TPB + 8 * tg + 4];
            double hd[8] = {(double)h0.x, (double)h0.y, (double)h0.z, (double)h0.w,
                            (double)h1.x, (double)h1.y, (double)h1.z, (double)h1.w};
            double wd[4] = {(double)w.x, (double)w.y, (double)w.z, (double)w.w};
#pragma unroll
            for (int i = 0; i < 8; ++i)
#pragma unroll
                for (int j = 0; j < 4; ++j)
                    acc[i][j] = fma(hd[i], wd[j], acc[i][j]);
        }
    }

    // dump fp64 logits to LDS [token][LSTRIDE]
    __syncthreads();
#pragma unroll
    for (int i = 0; i < 8; ++i)
#pragma unroll
        for (int j = 0; j < 4; ++j)
            sdl[(size_t)(8 * tg + i) * LSTRIDE + 4 * eg + j] = acc[i][j];
    __syncthreads();

    // zero dispatch & combine for this block's tokens (d_out is poisoned)
    {
        float4 z4 = make_float4(0.f, 0.f, 0.f, 0.f);
        float4* dp = (float4*)(dispatch + (size_t)tokBase * NE);
        float4* cp = (float4*)(combine + (size_t)tokBase * NE);
#pragma unroll
        for (int m = 0; m < 8; ++m) {
            dp[m * 256 + tid] = z4;
            cp[m * 256 + tid] = z4;
        }
    }

    float p2 = 0.f, zl = 0.f;
    if (tid < TPB) {
        const int t = tid;
        const double* rowd = &sdl[(size_t)t * LSTRIDE];

        // pass A: max + top-2 logits (fp64 decisions; strict > => lowest
        // index wins ties, matching lax.top_k)
        double mx = -1.0e300;
        double b0 = -1.0e300, b1 = -1.0e300;
        int i0 = 0, i1 = 0;
        for (int e = 0; e < NE; ++e) {
            double l = rowd[e];
            mx = fmax(mx, l);
            if (l > b0)      { b1 = b0; i1 = i0; b0 = l; i0 = e; }
            else if (l > b1) { b1 = l; i1 = e; }
        }

        // pass B: fp64 exp + sum; keep fp32 copies for probs output
        float fp[NE];
        double sum = 0.0;
#pragma unroll
        for (int e = 0; e < NE; ++e) {
            double ds = exp(rowd[e] - mx);
            sum += ds;
            fp[e] = (float)ds;
        }
        float sumf = (float)sum;

        // pass C: probs + aux partial
        float p2l = 0.f;
#pragma unroll
        for (int e = 0; e < NE; ++e) {
            float p = fp[e] / sumf;
            fp[e] = p;
            p2l += p * p;
        }
        float4* gp = (float4*)(probs_out + (size_t)(tokBase + t) * NE);
#pragma unroll
        for (int q = 0; q < 16; ++q) gp[q] = *(float4*)&fp[4 * q];

        p2 = p2l;
        double lse = mx + log(sum);
        zl = (float)(lse * lse);

        // renormalized top-2 weights in fp64: w0 = p0/(p0+p1) = 1/(1+exp(l1-l0))
        double w0 = 1.0 / (1.0 + exp(b1 - b0));
        double w1 = 1.0 / (1.0 + exp(b0 - b1));
        idx_buf[(size_t)(tokBase + t) * 2 + 0] = i0;
        idx_buf[(size_t)(tokBase + t) * 2 + 1] = i1;
        wgt_buf[(size_t)(tokBase + t) * 2 + 0] = (float)w0;
        wgt_buf[(size_t)(tokBase + t) * 2 + 1] = (float)w1;
    }

    // block-reduce loss partials (deterministic; waves 2,3 contribute zeros)
#pragma unroll
    for (int off = 32; off; off >>= 1) {
        p2 += __shfl_down(p2, off);
        zl += __shfl_down(zl, off);
    }
    const int lane = tid & 63, wid = tid >> 6;
    if (lane == 0) { red1[wid] = p2; red2[wid] = zl; }
    __syncthreads();
    if (tid == 0) {
        partials[blockIdx.x * 2 + 0] = red1[0] + red1[1] + red1[2] + red1[3];
        partials[blockIdx.x * 2 + 1] = red2[0] + red2[1] + red2[2] + red2[3];
    }
}

// ---------------------------------------------------------------------------
// Kernel 2: capacity-limited dispatch. One block per (batch, expert).
// Scans the 8192 k-major assignments of the batch in order, exact exclusive
// cumsum via ballot prefix + wave-count scan.
// ---------------------------------------------------------------------------
__global__ __launch_bounds__(256) void k_dispatch(
    const int* __restrict__ idx_buf, const float* __restrict__ wgt_buf,
    float* __restrict__ dispatch, float* __restrict__ combine)
{
    const int e = blockIdx.x & 63;
    const int b = blockIdx.x >> 6;
    __shared__ int wc[4];
    const int tid = threadIdx.x;
    const int lane = tid & 63, wid = tid >> 6;
    const int base = b * SEQ;

    int running = 0;
    for (int chunk = 0; chunk < 32; ++chunk) {
        int j = chunk * 256 + tid;         // k-major order: j = k*SEQ + s
        int k = j >> 12;
        int s = j & (SEQ - 1);
        int my = idx_buf[(size_t)(base + s) * 2 + k];
        bool m = (my == e);
        unsigned long long bal = __ballot(m);
        int prefix = __popcll(bal & ((1ull << lane) - 1ull));
        if (lane == 0) wc[wid] = __popcll(bal);
        __syncthreads();
        int woff = 0, tot = 0;
#pragma unroll
        for (int w = 0; w < 4; ++w) {
            int c = wc[w];
            tot += c;
            if (w < wid) woff += c;
        }
        if (m) {
            int pos = running + woff + prefix;
            if (pos < CAP) {
                size_t o = (size_t)(base + s) * NE + e;
                dispatch[o] = 1.0f;
                combine[o] = wgt_buf[(size_t)(base + s) * 2 + k];
            }
        }
        running += tot;
        __syncthreads();
    }
}

// ---------------------------------------------------------------------------
// Kernel 3: deterministic final reduce of 256 loss partials
// ---------------------------------------------------------------------------
__global__ __launch_bounds__(256) void k_final(
    const float* __restrict__ partials, float* __restrict__ out)
{
    __shared__ float r1[4], r2[4];
    const int tid = threadIdx.x;
    float a = partials[tid * 2 + 0];
    float b = partials[tid * 2 + 1];
#pragma unroll
    for (int off = 32; off; off >>= 1) {
        a += __shfl_down(a, off);
        b += __shfl_down(b, off);
    }
    const int lane = tid & 63, wid = tid >> 6;
    if (lane == 0) { r1[wid] = a; r2[wid] = b; }
    __syncthreads();
    if (tid == 0) {
        float at = r1[0] + r1[1] + r1[2] + r1[3];
        float bt = r2[0] + r2[1] + r2[2] + r2[3];
        out[0] = at / (float)NTOK * (float)NE;   // aux_loss
        out[1] = bt / (float)NTOK;               // z_loss
    }
}

extern "C" void kernel_launch(void* const* d_in, const int* in_sizes, int n_in,
                              void* d_out, int out_size, void* d_ws, size_t ws_size,
                              hipStream_t stream)
{
    const float* hs = (const float*)d_in[0];   // [8,4096,4096]
    const float* rw = (const float*)d_in[1];   // [64,4096]
    float* out = (float*)d_out;
    float* dispatch = out;                     // [B,S,E] = 2097152
    float* combine  = out + 2097152;
    float* probs    = out + 2 * 2097152;
    float* scalars  = out + 3 * 2097152;       // aux, z

    int*   idx_buf  = (int*)d_ws;                               // 65536 ints
    float* wgt_buf  = (float*)((char*)d_ws + 65536 * 4);        // 65536 floats
    float* partials = (float*)((char*)d_ws + 65536 * 8);        // 512 floats

    hipLaunchKernelGGL(k_router, dim3(NTOK / TPB), dim3(256), 0, stream,
                       hs, rw, dispatch, combine, probs, idx_buf, wgt_buf, partials);
    hipLaunchKernelGGL(k_dispatch, dim3(8 * NE), dim3(256), 0, stream,
                       idx_buf, wgt_buf, dispatch, combine);
    hipLaunchKernelGGL(k_final, dim3(1), dim3(256), 0, stream,
                       partials, scalars);
}